// Round 4
// baseline (8639.893 us; speedup 1.0000x reference)
//
#include <hip/hip_runtime.h>

// VQ-VAE nearest centroid — bit-exact emulation of the reference fp32 pipeline.
// Model of the reference ("np"):
//   S[i,k]  = x.c^T element: single-accumulator ascending-k fp32 FMA chain.
//   nx2/nc2 = PLAIN SEQUENTIAL ascending sum r = fl(r + fl(v*v)), no FMA.
//   dist    = fl( fl(-2*S + nx2) + nc2 );  argmin strict-< (first min).
//
// Layout: lane pair per row; even lane holds x[row][0:128] in VGPRs, odd holds
// x[row][128:256]. Ascending-d dot chain software-pipelined across the pair
// via shfl_xor(1): evens compute HEADS (d 0..127) of cols 4g..4g+3 while odds
// continue TAILS (d 128..255) of cols 4(g-1)..  512 FMAs/lane/iter.
//
// R1 FIX (rule #20): full `#pragma unroll` on the d-loop so a[d] indices are
// compile-time constants (partial unroll -> whole array in scratch, 16.5 GB
// of scratch traffic, VALUBusy 11%).
// R3 SAFEGUARD: `#pragma unroll 1` pins the 257-trip outer loop (suspected
// compile-time blowup killed two rounds).
// R4 FIX (load rematerialization): R3 landed at VGPR_Count=88 — the compiler
// avoided scratch by RE-LOADING a[d] from global x inside every g-iteration
// (x is const __restrict__, so remat of the load is legal). ~2 KB/lane/iter
// of per-lane-distinct L1/L2 traffic swamped the FMAs: VALUBusy 13%, dur
// 7.4 ms. The asm "+v" pins below make each loaded component the result of
// an opaque asm op -> not rematerializable -> the allocator must keep the
// x-row in VGPRs (fits: ~170 < 256 cap from __launch_bounds__(256,2)).
// Zero emitted instructions, no numeric change.

#define K_CENT 1024
#define DIM    256
#define RPB    128            // rows per block (256 threads, 2 lanes/row)

__device__ __forceinline__ float fmul(float a, float b) { return __fmul_rn(a, b); }
__device__ __forceinline__ float fadd(float a, float b) { return __fadd_rn(a, b); }

// ---- |c_k|^2: sequential ascending chain, one thread per centroid ----
__global__ __launch_bounds__(256)
void nc2_kernel(const float* __restrict__ c, float* __restrict__ nc2) {
    int k = blockIdx.x * blockDim.x + threadIdx.x;
    if (k >= K_CENT) return;
    const float* p = c + k * DIM;
    float r = 0.0f;
    #pragma unroll 1
    for (int d = 0; d < DIM; ++d) r = fadd(r, fmul(p[d], p[d]));
    nc2[k] = r;
}

__global__ __launch_bounds__(256, 2)
void vq_main(const float* __restrict__ x, const float* __restrict__ c,
             const float* __restrict__ nc2g, float* __restrict__ out) {
    const float4* __restrict__ x4 = (const float4*)x;
    const float4* __restrict__ c4 = (const float4*)c;
    float4* __restrict__ out4 = (float4*)out;

    __shared__ float cn2s[K_CENT];
    __shared__ int   bidx[RPB];

    const int t = threadIdx.x;
    for (int i = t; i < K_CENT; i += 256) cn2s[i] = nc2g[i];
    __syncthreads();

    const int rl       = t >> 1;          // local row 0..127
    const int half     = t & 1;           // 0: d[0,128)  1: d[128,256)
    const int rowsBase = blockIdx.x * RPB;
    const int row_g    = rowsBase + rl;

    // my half of the x row (32 float4 = 128 VGPRs)
    float4 a[32];
    {
        const float4* __restrict__ xp = x4 + (row_g << 6) + (half << 5);
        #pragma unroll
        for (int i = 0; i < 32; ++i) a[i] = xp[i];
    }
    // R4: opaque pins — defeat load-rematerialization so the x-row STAYS in
    // VGPRs across the whole g-loop (see header). No instructions emitted.
    #pragma unroll
    for (int i = 0; i < 32; ++i) {
        asm volatile("" : "+v"(a[i].x), "+v"(a[i].y), "+v"(a[i].z), "+v"(a[i].w));
    }

    // ---- nx2: sequential ascending chain across the lane pair.
    float part = 0.0f;
    if (half == 0) {
        #pragma unroll
        for (int i = 0; i < 32; ++i) {
            part = fadd(part, fmul(a[i].x, a[i].x));
            part = fadd(part, fmul(a[i].y, a[i].y));
            part = fadd(part, fmul(a[i].z, a[i].z));
            part = fadd(part, fmul(a[i].w, a[i].w));
        }
    }
    float nx2 = __shfl_xor(part, 1, 64);  // odd lane: even's partial; even: 0
    if (half == 1) {
        #pragma unroll
        for (int i = 0; i < 32; ++i) {
            nx2 = fadd(nx2, fmul(a[i].x, a[i].x));
            nx2 = fadd(nx2, fmul(a[i].y, a[i].y));
            nx2 = fadd(nx2, fmul(a[i].z, a[i].z));
            nx2 = fadd(nx2, fmul(a[i].w, a[i].w));
        }
    }

    // ---- pipelined scan: evens do heads of group g, odds do tails of g-1.
    float h0 = 0.f, h1 = 0.f, h2 = 0.f, h3 = 0.f;
    float best = 3.4e38f;
    int   bi   = 0;
    const int hoff = half << 5;

    #pragma unroll 1
    for (int g = 0; g <= 256; ++g) {
        float s0 = __shfl_xor(h0, 1, 64);
        float s1 = __shfl_xor(h1, 1, 64);
        float s2 = __shfl_xor(h2, 1, 64);
        float s3 = __shfl_xor(h3, 1, 64);

        int colbase = (half ? (4 * (g - 1)) : (4 * g)) & (K_CENT - 1);
        const float4* __restrict__ cp0 = c4 + ((colbase + 0) << 6) + hoff;
        const float4* __restrict__ cp1 = c4 + ((colbase + 1) << 6) + hoff;
        const float4* __restrict__ cp2 = c4 + ((colbase + 2) << 6) + hoff;
        const float4* __restrict__ cp3 = c4 + ((colbase + 3) << 6) + hoff;

        float a0 = half ? s0 : 0.0f;      // odd: continue chain from head
        float a1 = half ? s1 : 0.0f;
        float a2 = half ? s2 : 0.0f;
        float a3 = half ? s3 : 0.0f;

        // FULL unroll: compile-time a[d] indices keep the x-row in VGPRs.
        #pragma unroll
        for (int d = 0; d < 32; ++d) {
            float4 xv = a[d];
            float4 c0 = cp0[d], c1 = cp1[d], c2 = cp2[d], c3 = cp3[d];
            a0 = fmaf(xv.x, c0.x, a0); a0 = fmaf(xv.y, c0.y, a0);
            a0 = fmaf(xv.z, c0.z, a0); a0 = fmaf(xv.w, c0.w, a0);
            a1 = fmaf(xv.x, c1.x, a1); a1 = fmaf(xv.y, c1.y, a1);
            a1 = fmaf(xv.z, c1.z, a1); a1 = fmaf(xv.w, c1.w, a1);
            a2 = fmaf(xv.x, c2.x, a2); a2 = fmaf(xv.y, c2.y, a2);
            a2 = fmaf(xv.z, c2.z, a2); a2 = fmaf(xv.w, c2.w, a2);
            a3 = fmaf(xv.x, c3.x, a3); a3 = fmaf(xv.y, c3.y, a3);
            a3 = fmaf(xv.z, c3.z, a3); a3 = fmaf(xv.w, c3.w, a3);
        }

        h0 = a0; h1 = a1; h2 = a2; h3 = a3;

        if (g >= 1) {                      // odd lanes hold full dots for kbase..+3
            int kbase = 4 * (g - 1);
            float m0 = fadd(fadd(fmul(-2.0f, a0), nx2), cn2s[kbase + 0]);
            float m1 = fadd(fadd(fmul(-2.0f, a1), nx2), cn2s[kbase + 1]);
            float m2 = fadd(fadd(fmul(-2.0f, a2), nx2), cn2s[kbase + 2]);
            float m3 = fadd(fadd(fmul(-2.0f, a3), nx2), cn2s[kbase + 3]);
            if (m0 < best) { best = m0; bi = kbase + 0; }
            if (m1 < best) { best = m1; bi = kbase + 1; }
            if (m2 < best) { best = m2; bi = kbase + 2; }
            if (m3 < best) { best = m3; bi = kbase + 3; }
        }
    }

    if (half) bidx[rl] = bi;              // odd lane owns the row's answer
    __syncthreads();

    // ---- coalesced gather: out[rows] = c[bidx[row]] (bit-copies).
    #pragma unroll
    for (int k = 0; k < 32; ++k) {
        int L = t + (k << 8);
        int r = L >> 6, v = L & 63;
        out4[((rowsBase + r) << 6) + v] = c4[(bidx[r] << 6) + v];
    }
}

extern "C" void kernel_launch(void* const* d_in, const int* in_sizes, int n_in,
                              void* d_out, int out_size, void* d_ws, size_t ws_size,
                              hipStream_t stream) {
    const float* x = (const float*)d_in[0];
    const float* c = (const float*)d_in[1];
    float* out = (float*)d_out;
    float* nc2 = (float*)d_ws;           // 4 KiB scratch

    nc2_kernel<<<(K_CENT + 255) / 256, 256, 0, stream>>>(c, nc2);

    const int n_rows = in_sizes[0] / DIM;   // 131072
    vq_main<<<n_rows / RPB, 256, 0, stream>>>(x, c, nc2, out);
}

// Round 7
// 1139.217 us; speedup vs baseline: 7.5841x; 7.5841x over previous
//
#include <hip/hip_runtime.h>

// VQ-VAE nearest centroid — bit-exact emulation of the reference fp32 pipeline.
//   S[i,k]  = single-accumulator ascending-d fp32 FMA chain (d = 0..255).
//   nx2/nc2 = plain sequential ascending sum r = fl(r + fl(v*v)) (mul+add, no FMA).
//   dist    = fl( fl(-2*S + nx2) + nc2 );  argmin strict-< (first min wins).
//
// R6 REWRITE: R5 (XOR-swizzled tiles) failed correctness; rewritten with a
// minimal-risk layout instead of patched. Tiles stored TRANSPOSED in LDS
// ([quad][index]) and threads own STRIDE-16 rows/cols (row = 16j+ty,
// col = 16i+tx): wave b128 reads then hit banks 4*tx%32 / 4*ty%32 = 2-way
// conflicts (free), with plain affine indexing — no swizzle anywhere.
//   block tile 128x128, 16x16 threads, 8x8 accs/thread (static indices only),
//   32-d chunks staged per kc; nx2 accumulated from the staged chunks during
//   ct==0 (exact ascending chain). Per dq: 16 ds_read_b128 (~192cy) vs 256
//   FMA (~512cy) -> VALU-bound.
// Argmin: per-thread cols ascending with strict < (first min), then
// lexicographic (dist, index) shuffle merge across the 16 tx lanes.
// (R7: RESUBMISSION — R6 bench died to "container failed twice", the same
// infra signature as R1/R2; audit found no deadlock/OOB/compile-blowup/
// resource overrun in the kernel, and harness logs show multi-kB-s push
// timeouts in passing rounds. Source identical to R6.)

#define K_CENT 1024
#define DIM    256
#define BM     128           // rows per block
#define BN     128           // cols per tile iteration
#define NCT    (K_CENT/BN)   // 8 col tiles
#define NKC    (DIM/32)      // 8 k-chunks of 32 d's

__device__ __forceinline__ float fmul(float a, float b) { return __fmul_rn(a, b); }
__device__ __forceinline__ float fadd(float a, float b) { return __fadd_rn(a, b); }

// ---- |c_k|^2: sequential ascending chain, one thread per centroid ----
__global__ __launch_bounds__(256)
void nc2_kernel(const float* __restrict__ c, float* __restrict__ nc2) {
    int k = blockIdx.x * blockDim.x + threadIdx.x;
    if (k >= K_CENT) return;
    const float* p = c + k * DIM;
    float r = 0.0f;
    #pragma unroll 1
    for (int d = 0; d < DIM; ++d) r = fadd(r, fmul(p[d], p[d]));
    nc2[k] = r;
}

__global__ __launch_bounds__(256, 2)
void vq_main(const float* __restrict__ x, const float* __restrict__ c,
             const float* __restrict__ nc2g, float* __restrict__ out) {
    const float4* __restrict__ x4 = (const float4*)x;
    const float4* __restrict__ c4 = (const float4*)c;
    float4* __restrict__ out4 = (float4*)out;

    __shared__ float4 xsT[8][BM];     // 16 KB  [quad][row]
    __shared__ float4 csT[8][BN];     // 16 KB  [quad][col]
    __shared__ float  cn2s[K_CENT];   // 4 KB
    __shared__ float  nxs[BM];
    __shared__ int    bidxs[BM];

    const int t  = threadIdx.x;
    const int tx = t & 15;            // owns cols {16i + tx}
    const int ty = t >> 4;            // owns rows {16j + ty}
    const int rowsBase = blockIdx.x * BM;

    #pragma unroll 1
    for (int i = t; i < K_CENT; i += 256) cn2s[i] = nc2g[i];

    float nxacc = 0.0f;               // row-t |x|^2 chain, built during ct==0

    float best[8]; int bi[8];
    #pragma unroll
    for (int j = 0; j < 8; ++j) { best[j] = 3.4e38f; bi[j] = 0; }

    #pragma unroll 1
    for (int ct = 0; ct < NCT; ++ct) {
        float acc[8][8];
        #pragma unroll
        for (int j = 0; j < 8; ++j)
            #pragma unroll
            for (int i = 0; i < 8; ++i) acc[j][i] = 0.0f;

        #pragma unroll 1
        for (int kc = 0; kc < NKC; ++kc) {
            __syncthreads();          // prev readers done before overwrite
            // stage 32-d chunk, transposed: linear l = p*256+t -> (row,quad)
            #pragma unroll
            for (int p = 0; p < 4; ++p) {
                int idx = (p << 8) + t;
                int r = idx >> 3, q = idx & 7;
                xsT[q][r] = x4[((rowsBase + r) << 6) + (kc << 3) + q];
                csT[q][r] = c4[(((ct << 7) + r) << 6) + (kc << 3) + q];
            }
            __syncthreads();

            // nx2: exact sequential chain, kc/q/comp ascending = d 0..255.
            if (ct == 0 && t < BM) {
                #pragma unroll
                for (int q = 0; q < 8; ++q) {
                    float4 v = xsT[q][t];
                    nxacc = fadd(nxacc, fmul(v.x, v.x));
                    nxacc = fadd(nxacc, fmul(v.y, v.y));
                    nxacc = fadd(nxacc, fmul(v.z, v.z));
                    nxacc = fadd(nxacc, fmul(v.w, v.w));
                }
                if (kc == NKC - 1) nxs[t] = nxacc;
            }

            #pragma unroll 1
            for (int dq = 0; dq < 8; ++dq) {
                float4 xv[8], cv[8];
                #pragma unroll
                for (int j = 0; j < 8; ++j) xv[j] = xsT[dq][(j << 4) + ty];
                #pragma unroll
                for (int i = 0; i < 8; ++i) cv[i] = csT[dq][(i << 4) + tx];
                #pragma unroll
                for (int j = 0; j < 8; ++j)
                    #pragma unroll
                    for (int i = 0; i < 8; ++i) {
                        float s = acc[j][i];          // ascending d: x,y,z,w
                        s = fmaf(xv[j].x, cv[i].x, s);
                        s = fmaf(xv[j].y, cv[i].y, s);
                        s = fmaf(xv[j].z, cv[i].z, s);
                        s = fmaf(xv[j].w, cv[i].w, s);
                        acc[j][i] = s;
                    }
            }
        }
        __syncthreads();              // publishes nxs (ct==0); tiles idle now

        // ---- dist + thread-local argmin (cols ascending -> first-min).
        #pragma unroll
        for (int j = 0; j < 8; ++j) {
            float nx2v = nxs[(j << 4) + ty];
            #pragma unroll
            for (int i = 0; i < 8; ++i) {
                int kg = (ct << 7) + (i << 4) + tx;
                float m = fadd(fadd(fmul(-2.0f, acc[j][i]), nx2v), cn2s[kg]);
                if (m < best[j]) { best[j] = m; bi[j] = kg; }
            }
        }
    }

    // ---- merge across the 16 tx lanes: lexicographic (dist, index) min
    // preserves the global first-min tie rule.
    #pragma unroll
    for (int j = 0; j < 8; ++j) {
        float b = best[j]; int ii = bi[j];
        #pragma unroll
        for (int m = 1; m <= 8; m <<= 1) {
            float ob = __shfl_xor(b, m, 64);
            int   oi = __shfl_xor(ii, m, 64);
            if (ob < b || (ob == b && oi < ii)) { b = ob; ii = oi; }
        }
        if (tx == 0) bidxs[(j << 4) + ty] = ii;
    }
    __syncthreads();

    // ---- coalesced gather: out[rows] = c[bidx[row]] (bit-copies).
    #pragma unroll
    for (int k = 0; k < 32; ++k) {
        int L = t + (k << 8);
        int r = L >> 6, v = L & 63;
        out4[((rowsBase + r) << 6) + v] = c4[(bidxs[r] << 6) + v];
    }
}

extern "C" void kernel_launch(void* const* d_in, const int* in_sizes, int n_in,
                              void* d_out, int out_size, void* d_ws, size_t ws_size,
                              hipStream_t stream) {
    const float* x = (const float*)d_in[0];
    const float* c = (const float*)d_in[1];
    float* out = (float*)d_out;
    float* nc2 = (float*)d_ws;           // 4 KiB scratch

    nc2_kernel<<<(K_CENT + 255) / 256, 256, 0, stream>>>(c, nc2);

    const int n_rows = in_sizes[0] / DIM;   // 131072
    vq_main<<<n_rows / BM, 256, 0, stream>>>(x, c, nc2, out);
}

// Round 8
// 1126.164 us; speedup vs baseline: 7.6720x; 1.0116x over previous
//
#include <hip/hip_runtime.h>

// VQ-VAE nearest centroid — bit-exact emulation of the reference fp32 pipeline.
//   S[i,k]  = single-accumulator ascending-d fp32 FMA chain (d = 0..255).
//   nx2/nc2 = plain sequential ascending sum r = fl(r + fl(v*v)) (mul+add, no FMA).
//   dist    = fl( fl(-2*S + nx2) + nc2 );  argmin strict-< (first min wins).
//
// Structure (R6, verified 1139us): 128x128 block tile, 16x16 threads, 8x8
// accs/thread, 32-d chunks staged transposed in LDS ([quad][index]), threads
// own stride-16 rows/cols. Argmin: per-thread ascending strict-< + lexico
// (dist,index) shuffle merge.
//
// R8 FIXES (from R7 counters: SQ_LDS_BANK_CONFLICT=1.17e8 ~ 17% of CU-cycles):
//  (a) PAD rows to 129 float4: write addr bank was (4r)%32 independent of q,
//      so each staging octet (q=0..7, same r) hit ONE bank group 8-way.
//      With [8][129], bank = (4q+4r)%32 -> octet covers all 32 banks once ->
//      conflict-free writes. Reads stay free (xv broadcast, cv 2-way).
//  (b) dq-loop unroll 2: lets the compiler schedule dq+1's 16 ds_read_b128
//      under dq's 256 FMAs (xv/cv are loop-local, static-indexed after
//      unroll -> no rule-#20 scratch risk).

#define K_CENT 1024
#define DIM    256
#define BM     128           // rows per block
#define BN     128           // cols per tile iteration
#define NCT    (K_CENT/BN)   // 8 col tiles
#define NKC    (DIM/32)      // 8 k-chunks of 32 d's
#define LDP    (BM + 1)      // padded row stride (129) — bank-conflict fix

__device__ __forceinline__ float fmul(float a, float b) { return __fmul_rn(a, b); }
__device__ __forceinline__ float fadd(float a, float b) { return __fadd_rn(a, b); }

// ---- |c_k|^2: sequential ascending chain, one thread per centroid ----
__global__ __launch_bounds__(256)
void nc2_kernel(const float* __restrict__ c, float* __restrict__ nc2) {
    int k = blockIdx.x * blockDim.x + threadIdx.x;
    if (k >= K_CENT) return;
    const float* p = c + k * DIM;
    float r = 0.0f;
    #pragma unroll 1
    for (int d = 0; d < DIM; ++d) r = fadd(r, fmul(p[d], p[d]));
    nc2[k] = r;
}

__global__ __launch_bounds__(256, 2)
void vq_main(const float* __restrict__ x, const float* __restrict__ c,
             const float* __restrict__ nc2g, float* __restrict__ out) {
    const float4* __restrict__ x4 = (const float4*)x;
    const float4* __restrict__ c4 = (const float4*)c;
    float4* __restrict__ out4 = (float4*)out;

    __shared__ float4 xsT[8][LDP];    // [quad][row], padded
    __shared__ float4 csT[8][LDP];    // [quad][col], padded
    __shared__ float  cn2s[K_CENT];   // 4 KB
    __shared__ float  nxs[BM];
    __shared__ int    bidxs[BM];

    const int t  = threadIdx.x;
    const int tx = t & 15;            // owns cols {16i + tx}
    const int ty = t >> 4;            // owns rows {16j + ty}
    const int rowsBase = blockIdx.x * BM;

    #pragma unroll 1
    for (int i = t; i < K_CENT; i += 256) cn2s[i] = nc2g[i];

    float nxacc = 0.0f;               // row-t |x|^2 chain, built during ct==0

    float best[8]; int bi[8];
    #pragma unroll
    for (int j = 0; j < 8; ++j) { best[j] = 3.4e38f; bi[j] = 0; }

    #pragma unroll 1
    for (int ct = 0; ct < NCT; ++ct) {
        float acc[8][8];
        #pragma unroll
        for (int j = 0; j < 8; ++j)
            #pragma unroll
            for (int i = 0; i < 8; ++i) acc[j][i] = 0.0f;

        #pragma unroll 1
        for (int kc = 0; kc < NKC; ++kc) {
            __syncthreads();          // prev readers done before overwrite
            // stage 32-d chunk, transposed: linear l = p*256+t -> (row,quad)
            #pragma unroll
            for (int p = 0; p < 4; ++p) {
                int idx = (p << 8) + t;
                int r = idx >> 3, q = idx & 7;
                xsT[q][r] = x4[((rowsBase + r) << 6) + (kc << 3) + q];
                csT[q][r] = c4[(((ct << 7) + r) << 6) + (kc << 3) + q];
            }
            __syncthreads();

            // nx2: exact sequential chain, kc/q/comp ascending = d 0..255.
            if (ct == 0 && t < BM) {
                #pragma unroll
                for (int q = 0; q < 8; ++q) {
                    float4 v = xsT[q][t];
                    nxacc = fadd(nxacc, fmul(v.x, v.x));
                    nxacc = fadd(nxacc, fmul(v.y, v.y));
                    nxacc = fadd(nxacc, fmul(v.z, v.z));
                    nxacc = fadd(nxacc, fmul(v.w, v.w));
                }
                if (kc == NKC - 1) nxs[t] = nxacc;
            }

            #pragma unroll 2
            for (int dq = 0; dq < 8; ++dq) {
                float4 xv[8], cv[8];
                #pragma unroll
                for (int j = 0; j < 8; ++j) xv[j] = xsT[dq][(j << 4) + ty];
                #pragma unroll
                for (int i = 0; i < 8; ++i) cv[i] = csT[dq][(i << 4) + tx];
                #pragma unroll
                for (int j = 0; j < 8; ++j)
                    #pragma unroll
                    for (int i = 0; i < 8; ++i) {
                        float s = acc[j][i];          // ascending d: x,y,z,w
                        s = fmaf(xv[j].x, cv[i].x, s);
                        s = fmaf(xv[j].y, cv[i].y, s);
                        s = fmaf(xv[j].z, cv[i].z, s);
                        s = fmaf(xv[j].w, cv[i].w, s);
                        acc[j][i] = s;
                    }
            }
        }
        __syncthreads();              // publishes nxs (ct==0); tiles idle now

        // ---- dist + thread-local argmin (cols ascending -> first-min).
        #pragma unroll
        for (int j = 0; j < 8; ++j) {
            float nx2v = nxs[(j << 4) + ty];
            #pragma unroll
            for (int i = 0; i < 8; ++i) {
                int kg = (ct << 7) + (i << 4) + tx;
                float m = fadd(fadd(fmul(-2.0f, acc[j][i]), nx2v), cn2s[kg]);
                if (m < best[j]) { best[j] = m; bi[j] = kg; }
            }
        }
    }

    // ---- merge across the 16 tx lanes: lexicographic (dist, index) min
    // preserves the global first-min tie rule.
    #pragma unroll
    for (int j = 0; j < 8; ++j) {
        float b = best[j]; int ii = bi[j];
        #pragma unroll
        for (int m = 1; m <= 8; m <<= 1) {
            float ob = __shfl_xor(b, m, 64);
            int   oi = __shfl_xor(ii, m, 64);
            if (ob < b || (ob == b && oi < ii)) { b = ob; ii = oi; }
        }
        if (tx == 0) bidxs[(j << 4) + ty] = ii;
    }
    __syncthreads();

    // ---- coalesced gather: out[rows] = c[bidx[row]] (bit-copies).
    #pragma unroll
    for (int k = 0; k < 32; ++k) {
        int L = t + (k << 8);
        int r = L >> 6, v = L & 63;
        out4[((rowsBase + r) << 6) + v] = c4[(bidxs[r] << 6) + v];
    }
}

extern "C" void kernel_launch(void* const* d_in, const int* in_sizes, int n_in,
                              void* d_out, int out_size, void* d_ws, size_t ws_size,
                              hipStream_t stream) {
    const float* x = (const float*)d_in[0];
    const float* c = (const float*)d_in[1];
    float* out = (float*)d_out;
    float* nc2 = (float*)d_ws;           // 4 KiB scratch

    nc2_kernel<<<(K_CENT + 255) / 256, 256, 0, stream>>>(c, nc2);

    const int n_rows = in_sizes[0] / DIM;   // 131072
    vq_main<<<n_rows / BM, 256, 0, stream>>>(x, c, nc2, out);
}